// Round 7
// baseline (868.925 us; speedup 1.0000x reference)
//
#include <hip/hip_runtime.h>
#include <hip/hip_bf16.h>
#include <stdint.h>

typedef __bf16 bf16x8 __attribute__((ext_vector_type(8)));
typedef __bf16 bf16x4 __attribute__((ext_vector_type(4)));
typedef float  f32x4  __attribute__((ext_vector_type(4)));

typedef __attribute__((address_space(3))) unsigned int as3_uint;
typedef const __attribute__((address_space(1))) unsigned int as1_uint;

#define NEGC (-1e9f)

__device__ __forceinline__ void async16(void* ldsPtr, const void* gPtr) {
    __builtin_amdgcn_global_load_lds((as1_uint*)(uintptr_t)gPtr,
                                     (as3_uint*)(uintptr_t)ldsPtr, 16, 0, 0);
}

// ---------------- LayerNorm: f32 in -> bf16 out ----------------
__global__ __launch_bounds__(256) void ln_kernel(const float* __restrict__ x,
                                                 const float* __restrict__ gw,
                                                 const float* __restrict__ bw,
                                                 __bf16* __restrict__ xn) {
    __shared__ float red[8];
    size_t row = blockIdx.x;
    int t = threadIdx.x;
    const float4* xr = (const float4*)(x + row * 1024);
    float4 v = xr[t];
    float s  = v.x + v.y + v.z + v.w;
    float ss = v.x*v.x + v.y*v.y + v.z*v.z + v.w*v.w;
    #pragma unroll
    for (int o = 32; o; o >>= 1) { s += __shfl_xor(s, o); ss += __shfl_xor(ss, o); }
    int wave = t >> 6, lane = t & 63;
    if (lane == 0) { red[wave*2] = s; red[wave*2+1] = ss; }
    __syncthreads();
    float S  = red[0] + red[2] + red[4] + red[6];
    float SS = red[1] + red[3] + red[5] + red[7];
    float mu  = S * (1.0f/1024.0f);
    float var = SS * (1.0f/1024.0f) - mu*mu;
    float rs  = rsqrtf(var + 1e-5f);
    float4 gv = ((const float4*)gw)[t];
    float4 bv = ((const float4*)bw)[t];
    bf16x4 o4;
    o4[0] = (__bf16)((v.x-mu)*rs*gv.x + bv.x);
    o4[1] = (__bf16)((v.y-mu)*rs*gv.y + bv.y);
    o4[2] = (__bf16)((v.z-mu)*rs*gv.z + bv.z);
    o4[3] = (__bf16)((v.w-mu)*rs*gv.w + bv.w);
    ((bf16x4*)(xn + row*1024))[t] = o4;
}

// ---------------- PHM weight builder ----------------
// TILED==0: W^T row-major (nn*kout rows x nn*kin cols) bf16.
// TILED==1: staged-tile layout matching gemm256's STAGE_B:
//   elem(nrow,kcol) -> ((nt*KT + ktile)*16 + (kk2>>3)*4 + (rr>>6))*512
//                      + (rr&63)*8 + (kk2&7)
//   with nt=nrow>>8, rr=nrow&255, ktile=kcol>>5, kk2=kcol&31, KT=(nn*kin)/32.
template<int TILED>
__global__ __launch_bounds__(256) void phm_build(const float* __restrict__ A,
                                                 const float* __restrict__ S,
                                                 __bf16* __restrict__ Wt,
                                                 int nn, int kin, int kout) {
    __shared__ float sh[4][32][65];
    __shared__ float shA[64];
    int t  = threadIdx.x;
    int l0 = blockIdx.x * 64;
    int k0 = blockIdx.y * 32;
    int kt = nn * kin;  // 1024
    int KT = kt >> 5;
    if (t < nn*nn*nn) shA[t] = A[t];
    for (int n = 0; n < nn; ++n) {
        #pragma unroll
        for (int i = 0; i < 8; ++i) {
            int e = t + i*256;
            int kk = e >> 6, ll = e & 63;
            sh[n][kk][ll] = S[((size_t)(n*kin) + k0 + kk)*kout + l0 + ll];
        }
    }
    __syncthreads();
    for (int a = 0; a < nn; ++a)
        for (int b = 0; b < nn; ++b) {
            #pragma unroll
            for (int i = 0; i < 8; ++i) {
                int e = t + i*256;
                int kk = e & 31, ll = e >> 5;
                float val = 0.f;
                for (int n = 0; n < nn; ++n)
                    val += shA[(n*nn + a)*nn + b] * sh[n][kk][ll];
                int nrow = b*kout + l0 + ll;
                int kcol = a*kin + k0 + kk;
                if (TILED) {
                    int ntt = nrow >> 8, rr = nrow & 255;
                    int ktile = kcol >> 5, kk2 = kcol & 31;
                    size_t off = (((size_t)ntt*KT + ktile)*16 + (kk2>>3)*4 + (rr>>6))*512
                               + (rr & 63)*8 + (kk2 & 7);
                    Wt[off] = (__bf16)val;
                } else {
                    Wt[(size_t)nrow*kt + kcol] = (__bf16)val;
                }
            }
        }
}

// ---------------- gate weight (1024 x 16) f32 ----------------
__global__ __launch_bounds__(256) void gatew_kernel(const float* __restrict__ A,
                                                    const float* __restrict__ S,
                                                    float* __restrict__ W) {
    int idx = blockIdx.x*256 + threadIdx.x;      // 16384 total
    int r = idx >> 4, c = idx & 15;
    int a = r >> 8, k = r & 255, b = c >> 2, l = c & 3;
    float v = 0.f;
    #pragma unroll
    for (int n = 0; n < 4; ++n)
        v += A[(n*4 + a)*4 + b] * S[((size_t)(n*256 + k))*4 + l];
    W[idx] = v;
}

// ---------------- 128x128 bf16 MFMA GEMM (m97-style, proven): attn qk ------
__global__ __launch_bounds__(256) void gemm128(const __bf16* __restrict__ A,
                                               const __bf16* __restrict__ Bt,
                                               const float* __restrict__ bias,
                                               float* __restrict__ C,
                                               int M, int N, int K) {
    __shared__ __align__(16) __bf16 As[128*64];
    __shared__ __align__(16) __bf16 Bs[128*64];
    int tid  = threadIdx.x;
    int wave = tid >> 6, lane = tid & 63;
    int m0 = blockIdx.y * 128, n0 = blockIdx.x * 128;
    int wm = (wave >> 1) * 64, wn = (wave & 1) * 64;
    int lrow = lane & 15, lk = lane >> 4;
    f32x4 acc[4][4] = {};
    for (int k0 = 0; k0 < K; k0 += 64) {
        #pragma unroll
        for (int q = 0; q < 4; ++q) {
            int o   = q*4096 + tid*16;
            int row = o >> 7;
            int sp  = (o >> 4) & 7;
            int s   = sp ^ (row & 7);
            async16((char*)As + q*4096 + wave*1024,
                    (const char*)A  + ((size_t)(m0+row)*K + k0 + s*8)*2);
            async16((char*)Bs + q*4096 + wave*1024,
                    (const char*)Bt + ((size_t)(n0+row)*K + k0 + s*8)*2);
        }
        __syncthreads();
        #pragma unroll
        for (int kk = 0; kk < 2; ++kk) {
            bf16x8 af[4], bfr[4];
            #pragma unroll
            for (int mi = 0; mi < 4; ++mi) {
                int r = wm + mi*16 + lrow;
                int off = r*128 + ((kk*64 + lk*16) ^ ((r & 7) << 4));
                af[mi] = *(const bf16x8*)((const char*)As + off);
            }
            #pragma unroll
            for (int ni = 0; ni < 4; ++ni) {
                int r = wn + ni*16 + lrow;
                int off = r*128 + ((kk*64 + lk*16) ^ ((r & 7) << 4));
                bfr[ni] = *(const bf16x8*)((const char*)Bs + off);
            }
            #pragma unroll
            for (int mi = 0; mi < 4; ++mi)
                #pragma unroll
                for (int ni = 0; ni < 4; ++ni)
                    acc[mi][ni] = __builtin_amdgcn_mfma_f32_16x16x32_bf16(
                        af[mi], bfr[ni], acc[mi][ni], 0, 0, 0);
        }
        __syncthreads();
    }
    #pragma unroll
    for (int ni = 0; ni < 4; ++ni) {
        int col = n0 + wn + ni*16 + lrow;
        float bv = bias ? bias[col] : 0.f;
        #pragma unroll
        for (int mi = 0; mi < 4; ++mi) {
            #pragma unroll
            for (int r = 0; r < 4; ++r) {
                int rowg = m0 + wm + mi*16 + lk*4 + r;
                C[(size_t)rowg*N + col] = acc[mi][ni][r] + bv;
            }
        }
    }
}

// ---------------- 256x256 bf16 MFMA GEMM, BK=32, quad-buffered LDS ----------
// 512 thr / 8 waves (2m x 4n). LDS: A 4x16KB + B 4x16KB = 128KB, column-panel
// layout [lk][row][16B] -> conflict-free ds_read_b128 AND linear gload_lds dest.
// B source is PRE-TILED (phm_build<1>) so staging reads are fully linear; A
// (L2-resident xn) is row-major, strided source absorbed by L1/L2.
// Pipeline: stage tile T+3 during tile T; vmcnt(4) once per tile BEFORE issue
// certifies tile T+1 staged ~3 tiles (~1000 cyc) earlier -> HBM latency covered
// (the per-phase vmcnt over-drain was the measured 33%-util bug).
// 2 phases/tile: phA{vmcnt; stage A(T+3); read A-mh0+B; bar; lgkm; 16 MFMA; bar}
//                phB{stage B(T+3); read A-mh1; bar; lgkm; 16 MFMA; bar}
// Grid: 8 XCD x 250; block->tile pairs both m-tiles of an XCD per n-panel.
// BF16OUT==1: store bf16 at the FRONT of each f32 output row slot.
template<int BF16OUT>
__global__ __launch_bounds__(512, 2) void gemm256(const __bf16* __restrict__ A,
                                                  const __bf16* __restrict__ Btile,
                                                  const float* __restrict__ bias,
                                                  void* __restrict__ Cv,
                                                  int N, int K) {
    __shared__ __align__(16) char smem[131072];
    int tid = threadIdx.x;
    int wid = tid >> 6, lane = tid & 63;
    int l = blockIdx.x >> 3, xcd = blockIdx.x & 7;
    int mt = xcd * 2 + (l & 1), nt = l >> 1;
    int m0 = mt << 8, n0 = nt << 8;
    int wm = wid >> 2, wn = wid & 3;
    int lrow = lane & 15, lk = lane >> 4;
    int NT = K >> 5;                       // 32 K-tiles of 32

    f32x4 acc[8][4] = {};
    bf16x8 afr[4], bfr[4];

    auto STAGE_A = [&](int buf, int kt) {
        #pragma unroll
        for (int q = 0; q < 2; ++q) {
            int ch = q*8 + wid, plk = ch >> 2, r0 = (ch & 3) << 6;
            async16(smem + buf*16384 + ch*1024,
                    (const char*)A + (((size_t)(m0 + r0 + lane))*K + kt*32 + plk*8)*2);
        }
    };
    auto STAGE_B = [&](int buf, int kt) {
        #pragma unroll
        for (int q = 0; q < 2; ++q) {
            int ch = q*8 + wid;
            async16(smem + 65536 + buf*16384 + ch*1024,
                    (const char*)Btile + ((((size_t)nt*NT + kt)*16 + ch)*512 + lane*8)*2);
        }
    };
    auto LDA = [&](int buf, int mh) {
        const char* Ab = smem + buf*16384 + lk*4096;
        #pragma unroll
        for (int mf = 0; mf < 4; ++mf) {
            int row = wm*128 + mh*64 + mf*16 + lrow;
            afr[mf] = *(const bf16x8*)(Ab + row*16);
        }
    };
    auto LDB = [&](int buf) {
        const char* Bb = smem + 65536 + buf*16384 + lk*4096;
        #pragma unroll
        for (int nf = 0; nf < 4; ++nf) {
            int row = wn*64 + nf*16 + lrow;
            bfr[nf] = *(const bf16x8*)(Bb + row*16);
        }
    };
    auto MM = [&](int mh) {
        __builtin_amdgcn_s_setprio(1);
        #pragma unroll
        for (int mf = 0; mf < 4; ++mf)
            #pragma unroll
            for (int nf = 0; nf < 4; ++nf)
                acc[mh*4+mf][nf] = __builtin_amdgcn_mfma_f32_16x16x32_bf16(
                    afr[mf], bfr[nf], acc[mh*4+mf][nf], 0, 0, 0);
        __builtin_amdgcn_s_setprio(0);
    };

    // prologue: tiles 0,1,2 staged (12 instrs); certify tile 0
    STAGE_A(0,0); STAGE_B(0,0);
    STAGE_A(1,1); STAGE_B(1,1);
    STAGE_A(2,2); STAGE_B(2,2);
    asm volatile("s_waitcnt vmcnt(8)" ::: "memory");
    __builtin_amdgcn_s_barrier();

    for (int T = 0; T < NT; ++T) {
        int buf = T & 3;
        // ---- phase A (mh = 0)
        if (T + 2 < NT)      { asm volatile("s_waitcnt vmcnt(4)" ::: "memory"); }
        else if (T + 1 < NT) { asm volatile("s_waitcnt vmcnt(0)" ::: "memory"); }
        if (T + 3 < NT) STAGE_A((T+3)&3, T+3);
        LDA(buf, 0); LDB(buf);
        __builtin_amdgcn_s_barrier();
        asm volatile("s_waitcnt lgkmcnt(0)" ::: "memory");
        __builtin_amdgcn_sched_barrier(0);
        MM(0);
        __builtin_amdgcn_s_barrier();
        // ---- phase B (mh = 1)
        if (T + 3 < NT) STAGE_B((T+3)&3, T+3);
        LDA(buf, 1);
        __builtin_amdgcn_s_barrier();
        asm volatile("s_waitcnt lgkmcnt(0)" ::: "memory");
        __builtin_amdgcn_sched_barrier(0);
        MM(1);
        __builtin_amdgcn_s_barrier();
    }

    // epilogue: C/D layout col=lane&15, row=(lane>>4)*4+reg
    #pragma unroll
    for (int nf = 0; nf < 4; ++nf) {
        int col = n0 + wn*64 + nf*16 + lrow;
        float bv = bias ? bias[col] : 0.f;
        #pragma unroll
        for (int mf = 0; mf < 8; ++mf) {
            int rowg = m0 + wm*128 + mf*16 + lk*4;
            #pragma unroll
            for (int r = 0; r < 4; ++r) {
                float val = acc[mf][nf][r] + bv;
                if (BF16OUT) {
                    ((__bf16*)((char*)Cv + (size_t)(rowg + r) * N * 4))[col] = (__bf16)val;
                } else {
                    ((float*)Cv)[(size_t)(rowg + r) * N + col] = val;
                }
            }
        }
    }
}

// ---------------- gate: logits + softmax probs Gp (4096 x 16) ----------------
__global__ __launch_bounds__(256) void gate_kernel(const __bf16* __restrict__ xn,
                                                   const float* __restrict__ Wg,
                                                   const float* __restrict__ gb,
                                                   float* __restrict__ Gp) {
    __shared__ float xr[16][65];
    __shared__ float red[16][17];
    size_t row = blockIdx.x;
    int t = threadIdx.x;
    bf16x4 v = ((const bf16x4*)(xn + row*1024))[t];
    #pragma unroll
    for (int q = 0; q < 4; ++q) {
        int e = t*4 + q;
        xr[e >> 6][e & 63] = (float)v[q];
    }
    __syncthreads();
    int h = t & 15, sl = t >> 4;
    float p = 0.f;
    #pragma unroll
    for (int u = 0; u < 64; ++u) p += xr[sl][u] * Wg[(sl*64 + u)*16 + h];
    red[sl][h] = p;
    __syncthreads();
    if (t < 16) {
        float logit = gb[t];
        #pragma unroll
        for (int s2 = 0; s2 < 16; ++s2) logit += red[s2][t];
        float m = logit;
        #pragma unroll
        for (int o = 8; o; o >>= 1) m = fmaxf(m, __shfl_xor(m, o, 16));
        float e = __expf(logit - m);
        float ssum = e;
        #pragma unroll
        for (int o = 8; o; o >>= 1) ssum += __shfl_xor(ssum, o, 16);
        Gp[row*16 + t] = e / ssum;
    }
}

// ---------------- scores + masked log-softmax + head-logsumexp -> transition --
// v2: no max pass (|s| <= ~3 bounded: |q|,|k| norms ~5, s = q.k/8), so
// sum exp(s) directly; double-buffered partials -> ONE barrier per h.
__global__ __launch_bounds__(512) void scores_kernel(const float* __restrict__ qk,
                                                     const float* __restrict__ Gp,
                                                     const int* __restrict__ lens,
                                                     float* __restrict__ out) {
    __shared__ float qs[8][1024];
    __shared__ float gps[8][16];
    __shared__ float wredB[2][8][8];
    int b  = blockIdx.y;
    int i0 = blockIdx.x * 8;
    int t  = threadIdx.x;
    int wave = t >> 6, lane = t & 63;
    int len = lens[b];
    const float4* qbase = (const float4*)(qk + ((size_t)b*512 + i0)*2048);
    #pragma unroll
    for (int s = 0; s < 4; ++s) {
        int e = t + s*512;
        int ti = e >> 8, c4 = e & 255;
        ((float4*)qs)[e] = qbase[ti*512 + c4];
    }
    if (t < 128) {
        int ti = t >> 4, h = t & 15;
        gps[ti][h] = Gp[((size_t)b*512 + i0 + ti)*16 + h];
    }
    __syncthreads();
    int j = t;
    const float4* kp = (const float4*)(qk + ((size_t)b*512 + j)*2048 + 1024);
    float acc[8], mace[8];
    #pragma unroll
    for (int ti = 0; ti < 8; ++ti) { acc[ti] = 0.f; mace[ti] = 0.f; }
    for (int h = 0; h < 16; ++h) {
        float4 kv[16];
        #pragma unroll
        for (int u = 0; u < 16; ++u) kv[u] = kp[h*16 + u];
        float pex[8];
        #pragma unroll
        for (int ti = 0; ti < 8; ++ti) {
            const float* qrow = &qs[ti][h*64];
            float d = 0.f;
            #pragma unroll
            for (int u = 0; u < 16; ++u)
                d += kv[u].x*qrow[u*4+0] + kv[u].y*qrow[u*4+1]
                   + kv[u].z*qrow[u*4+2] + kv[u].w*qrow[u*4+3];
            int i = i0 + ti;
            float sc = (j > i && j < len) ? d * 0.125f : NEGC;
            float pe = __expf(sc);            // exp(NEG)=0 for invalid j
            pex[ti] = pe;
            float vv = pe;
            #pragma unroll
            for (int o = 32; o; o >>= 1) vv += __shfl_xor(vv, o);
            if (lane == 0) wredB[h & 1][wave][ti] = vv;
        }
        __syncthreads();
        #pragma unroll
        for (int ti = 0; ti < 8; ++ti) {
            float gs = 0.f;
            #pragma unroll
            for (int w = 0; w < 8; ++w) gs += wredB[h & 1][w][ti];
            float inv = 1.0f / gs;
            float g = gps[ti][h];
            acc[ti]  += pex[ti] * inv * g;
            mace[ti] += g * inv;
        }
    }
    #pragma unroll
    for (int ti = 0; ti < 8; ++ti) {
        int i = i0 + ti;
        float val;
        if (i >= len - 1)            val = NEGC;                     // dead row
        else if (j > i && j < len)   val = __logf(acc[ti]);          // valid successor
        else                         val = NEGC + __logf(mace[ti]);  // masked position
        out[((size_t)b*512 + i)*512 + j] = val;
    }
}

// ---------------- vocab: bf16 logits (front of own f32 row slot) ->
//                   in-place f32 log-softmax, row staged in LDS ----------------
__global__ __launch_bounds__(256) void vocab_softmax_bf16(float* __restrict__ out) {
    __shared__ __align__(16) __bf16 srow[32000];
    __shared__ float red[8];
    size_t row = blockIdx.x;
    char* rowbase = (char*)out + row * (size_t)32000 * 4;
    const bf16x8* g8 = (const bf16x8*)rowbase;
    bf16x8* s8 = (bf16x8*)srow;
    int t = threadIdx.x, wave = t >> 6, lane = t & 63;
    float mx = -1e30f;
    for (int v = t; v < 4000; v += 256) {
        bf16x8 c = g8[v];
        s8[v] = c;
        #pragma unroll
        for (int jj = 0; jj < 8; ++jj) mx = fmaxf(mx, (float)c[jj]);
    }
    #pragma unroll
    for (int o = 32; o; o >>= 1) mx = fmaxf(mx, __shfl_xor(mx, o));
    if (lane == 0) red[wave] = mx;
    __syncthreads();
    mx = fmaxf(fmaxf(red[0], red[1]), fmaxf(red[2], red[3]));
    float sum = 0.f;
    for (int v = t; v < 4000; v += 256) {
        bf16x8 c = s8[v];
        #pragma unroll
        for (int jj = 0; jj < 8; ++jj) sum += __expf((float)c[jj] - mx);
    }
    #pragma unroll
    for (int o = 32; o; o >>= 1) sum += __shfl_xor(sum, o);
    if (lane == 0) red[4 + wave] = sum;
    __syncthreads();
    float lse = mx + __logf(red[4] + red[5] + red[6] + red[7]);
    float4* o4 = (float4*)rowbase;
    for (int u = t; u < 8000; u += 256) {           // contiguous f32 stores
        bf16x4 c = *(const bf16x4*)(srow + u*4);
        float4 a;
        a.x = (float)c[0] - lse; a.y = (float)c[1] - lse;
        a.z = (float)c[2] - lse; a.w = (float)c[3] - lse;
        o4[u] = a;
    }
}

extern "C" void kernel_launch(void* const* d_in, const int* in_sizes, int n_in,
                              void* d_out, int out_size, void* d_ws, size_t ws_size,
                              hipStream_t stream) {
    (void)in_sizes; (void)n_in; (void)out_size; (void)ws_size;
    const float* x      = (const float*)d_in[0];
    const int*   lens   = (const int*)  d_in[1];
    const float* ln_g   = (const float*)d_in[2];
    const float* ln_b   = (const float*)d_in[3];
    const float* attn_A = (const float*)d_in[4];
    const float* attn_S = (const float*)d_in[5];
    const float* attn_b = (const float*)d_in[6];
    const float* gate_A = (const float*)d_in[7];
    const float* gate_S = (const float*)d_in[8];
    const float* gate_b = (const float*)d_in[9];
    const float* lm_A   = (const float*)d_in[10];
    const float* lm_S   = (const float*)d_in[11];
    const float* lm_b   = (const float*)d_in[12];

    float* out_trans = (float*)d_out;
    float* out_vocab = out_trans + (size_t)8*512*512;

    char* ws = (char*)d_ws;
    __bf16* xn     = (__bf16*)(ws);                 //  8,388,608 B
    __bf16* WtAttn = (__bf16*)(ws + 8388608);       //  4,194,304 B (row-major N x K)
    __bf16* WtLm   = (__bf16*)(ws + 12582912);      // 65,536,000 B (TILED layout)
    float*  Wg     = (float*) (ws + 78118912);      //     65,536 B
    float*  qkbuf  = (float*) (ws + 78184448);      // 33,554,432 B
    float*  Gp     = (float*) (ws + 111738880);     //    262,144 B

    hipLaunchKernelGGL(ln_kernel,    dim3(4096),     dim3(256), 0, stream, x, ln_g, ln_b, xn);
    hipLaunchKernelGGL(gatew_kernel, dim3(64),       dim3(256), 0, stream, gate_A, gate_S, Wg);
    hipLaunchKernelGGL((phm_build<0>), dim3(8, 8),   dim3(256), 0, stream, attn_A, attn_S, WtAttn, 4, 256, 512);
    hipLaunchKernelGGL((phm_build<1>), dim3(250, 16),dim3(256), 0, stream, lm_A, lm_S, WtLm, 2, 512, 16000);
    hipLaunchKernelGGL(gemm128,      dim3(16, 32),   dim3(256), 0, stream,
                       xn, WtAttn, attn_b, qkbuf, 4096, 2048, 1024);
    hipLaunchKernelGGL(gate_kernel,  dim3(4096),     dim3(256), 0, stream, xn, Wg, gate_b, Gp);
    hipLaunchKernelGGL(scores_kernel,dim3(64, 8),    dim3(512), 0, stream, qkbuf, Gp, lens, out_trans);
    hipLaunchKernelGGL((gemm256<1>), dim3(2000),     dim3(512), 0, stream,
                       xn, WtLm, lm_b, (void*)out_vocab, 32000, 1024);
    hipLaunchKernelGGL(vocab_softmax_bf16, dim3(4096), dim3(256), 0, stream, out_vocab);
}

// Round 8
// 837.285 us; speedup vs baseline: 1.0378x; 1.0378x over previous
//
#include <hip/hip_runtime.h>
#include <hip/hip_bf16.h>
#include <stdint.h>

typedef __bf16 bf16x8 __attribute__((ext_vector_type(8)));
typedef __bf16 bf16x4 __attribute__((ext_vector_type(4)));
typedef float  f32x4  __attribute__((ext_vector_type(4)));

typedef __attribute__((address_space(3))) unsigned int as3_uint;
typedef const __attribute__((address_space(1))) unsigned int as1_uint;

#define NEGC (-1e9f)

__device__ __forceinline__ void async16(void* ldsPtr, const void* gPtr) {
    __builtin_amdgcn_global_load_lds((as1_uint*)(uintptr_t)gPtr,
                                     (as3_uint*)(uintptr_t)ldsPtr, 16, 0, 0);
}

// ---------------- LayerNorm: f32 in -> bf16 out ----------------
__global__ __launch_bounds__(256) void ln_kernel(const float* __restrict__ x,
                                                 const float* __restrict__ gw,
                                                 const float* __restrict__ bw,
                                                 __bf16* __restrict__ xn) {
    __shared__ float red[8];
    size_t row = blockIdx.x;
    int t = threadIdx.x;
    const float4* xr = (const float4*)(x + row * 1024);
    float4 v = xr[t];
    float s  = v.x + v.y + v.z + v.w;
    float ss = v.x*v.x + v.y*v.y + v.z*v.z + v.w*v.w;
    #pragma unroll
    for (int o = 32; o; o >>= 1) { s += __shfl_xor(s, o); ss += __shfl_xor(ss, o); }
    int wave = t >> 6, lane = t & 63;
    if (lane == 0) { red[wave*2] = s; red[wave*2+1] = ss; }
    __syncthreads();
    float S  = red[0] + red[2] + red[4] + red[6];
    float SS = red[1] + red[3] + red[5] + red[7];
    float mu  = S * (1.0f/1024.0f);
    float var = SS * (1.0f/1024.0f) - mu*mu;
    float rs  = rsqrtf(var + 1e-5f);
    float4 gv = ((const float4*)gw)[t];
    float4 bv = ((const float4*)bw)[t];
    bf16x4 o4;
    o4[0] = (__bf16)((v.x-mu)*rs*gv.x + bv.x);
    o4[1] = (__bf16)((v.y-mu)*rs*gv.y + bv.y);
    o4[2] = (__bf16)((v.z-mu)*rs*gv.z + bv.z);
    o4[3] = (__bf16)((v.w-mu)*rs*gv.w + bv.w);
    ((bf16x4*)(xn + row*1024))[t] = o4;
}

// ---------------- PHM weight builder: W^T (nn*kout rows x nn*kin cols) bf16 ----------------
__global__ __launch_bounds__(256) void phm_build(const float* __restrict__ A,
                                                 const float* __restrict__ S,
                                                 __bf16* __restrict__ Wt,
                                                 int nn, int kin, int kout) {
    __shared__ float sh[4][32][65];
    __shared__ float shA[64];
    int t  = threadIdx.x;
    int l0 = blockIdx.x * 64;
    int k0 = blockIdx.y * 32;
    int kt = nn * kin;  // 1024
    if (t < nn*nn*nn) shA[t] = A[t];
    for (int n = 0; n < nn; ++n) {
        #pragma unroll
        for (int i = 0; i < 8; ++i) {
            int e = t + i*256;
            int kk = e >> 6, ll = e & 63;
            sh[n][kk][ll] = S[((size_t)(n*kin) + k0 + kk)*kout + l0 + ll];
        }
    }
    __syncthreads();
    for (int a = 0; a < nn; ++a)
        for (int b = 0; b < nn; ++b) {
            #pragma unroll
            for (int i = 0; i < 8; ++i) {
                int e = t + i*256;
                int kk = e & 31, ll = e >> 5;
                float val = 0.f;
                for (int n = 0; n < nn; ++n)
                    val += shA[(n*nn + a)*nn + b] * sh[n][kk][ll];
                Wt[(size_t)(b*kout + l0 + ll)*kt + a*kin + k0 + kk] = (__bf16)val;
            }
        }
}

// ---------------- gate weight (1024 x 16) f32 ----------------
__global__ __launch_bounds__(256) void gatew_kernel(const float* __restrict__ A,
                                                    const float* __restrict__ S,
                                                    float* __restrict__ W) {
    int idx = blockIdx.x*256 + threadIdx.x;      // 16384 total
    int r = idx >> 4, c = idx & 15;
    int a = r >> 8, k = r & 255, b = c >> 2, l = c & 3;
    float v = 0.f;
    #pragma unroll
    for (int n = 0; n < 4; ++n)
        v += A[(n*4 + a)*4 + b] * S[((size_t)(n*256 + k))*4 + l];
    W[idx] = v;
}

// ---------------- bf16 MFMA GEMM: C = A(MxK) * Bt(NxK)^T + bias ----------------
// (Round-2 proven config: 340us / 35% MfmaUtil on the LM head. 128^2 tile,
//  m97 structure. Five 256^2 schedule variants all measured WORSE; parked.)
// SWZ==1: LM geometry hardcoded (M=4096, N=32000 -> 32 m-tiles x 250 n-tiles,
//   8000 blocks, 1D grid). XCD-bijective chunking + 8-m-tile bands.
// BF16OUT==1: store bf16 logits packed at the FRONT of each f32 output row slot.
template<int SWZ, int BF16OUT>
__global__ __launch_bounds__(256) void gemm_bt_t(const __bf16* __restrict__ A,
                                                 const __bf16* __restrict__ Bt,
                                                 const float* __restrict__ bias,
                                                 void* __restrict__ Cv,
                                                 int M, int N, int K) {
    __shared__ __align__(16) __bf16 As[128*64];
    __shared__ __align__(16) __bf16 Bs[128*64];
    int tid  = threadIdx.x;
    int wave = tid >> 6, lane = tid & 63;
    int m0, n0;
    if (SWZ) {
        int bid  = blockIdx.x;
        int wg   = (bid & 7) * 1000 + (bid >> 3);   // XCD-contiguous chunks
        int band = wg / 2000;                        // 4 bands of 8 m-tiles
        int rem  = wg % 2000;
        int nt   = rem >> 3;                         // 0..249
        int mt   = band * 8 + (rem & 7);             // 0..31
        m0 = mt * 128; n0 = nt * 128;
    } else {
        m0 = blockIdx.y * 128; n0 = blockIdx.x * 128;
    }
    int wm = (wave >> 1) * 64, wn = (wave & 1) * 64;
    int lrow = lane & 15, lk = lane >> 4;
    f32x4 acc[4][4] = {};
    for (int k0 = 0; k0 < K; k0 += 64) {
        #pragma unroll
        for (int q = 0; q < 4; ++q) {
            int o   = q*4096 + tid*16;
            int row = o >> 7;
            int sp  = (o >> 4) & 7;
            int s   = sp ^ (row & 7);
            async16((char*)As + q*4096 + wave*1024,
                    (const char*)A  + ((size_t)(m0+row)*K + k0 + s*8)*2);
            async16((char*)Bs + q*4096 + wave*1024,
                    (const char*)Bt + ((size_t)(n0+row)*K + k0 + s*8)*2);
        }
        __syncthreads();
        #pragma unroll
        for (int kk = 0; kk < 2; ++kk) {
            bf16x8 af[4], bfr[4];
            #pragma unroll
            for (int mi = 0; mi < 4; ++mi) {
                int r = wm + mi*16 + lrow;
                int off = r*128 + ((kk*64 + lk*16) ^ ((r & 7) << 4));
                af[mi] = *(const bf16x8*)((const char*)As + off);
            }
            #pragma unroll
            for (int ni = 0; ni < 4; ++ni) {
                int r = wn + ni*16 + lrow;
                int off = r*128 + ((kk*64 + lk*16) ^ ((r & 7) << 4));
                bfr[ni] = *(const bf16x8*)((const char*)Bs + off);
            }
            #pragma unroll
            for (int mi = 0; mi < 4; ++mi)
                #pragma unroll
                for (int ni = 0; ni < 4; ++ni)
                    acc[mi][ni] = __builtin_amdgcn_mfma_f32_16x16x32_bf16(
                        af[mi], bfr[ni], acc[mi][ni], 0, 0, 0);
        }
        __syncthreads();
    }
    #pragma unroll
    for (int ni = 0; ni < 4; ++ni) {
        int col = n0 + wn + ni*16 + lrow;
        float bv = bias ? bias[col] : 0.f;
        #pragma unroll
        for (int mi = 0; mi < 4; ++mi) {
            #pragma unroll
            for (int r = 0; r < 4; ++r) {
                int rowg = m0 + wm + mi*16 + lk*4 + r;   // C/D: col=lane&15, row=(lane>>4)*4+reg
                float val = acc[mi][ni][r] + bv;
                if (BF16OUT) {
                    __bf16* rowp = (__bf16*)((char*)Cv + (size_t)rowg*N*4);
                    rowp[col] = (__bf16)val;
                } else {
                    ((float*)Cv)[(size_t)rowg*N + col] = val;
                }
            }
        }
    }
}

// ---------------- gate: logits + softmax probs Gp (4096 x 16) ----------------
__global__ __launch_bounds__(256) void gate_kernel(const __bf16* __restrict__ xn,
                                                   const float* __restrict__ Wg,
                                                   const float* __restrict__ gb,
                                                   float* __restrict__ Gp) {
    __shared__ float xr[16][65];
    __shared__ float red[16][17];
    size_t row = blockIdx.x;
    int t = threadIdx.x;
    bf16x4 v = ((const bf16x4*)(xn + row*1024))[t];
    #pragma unroll
    for (int q = 0; q < 4; ++q) {
        int e = t*4 + q;
        xr[e >> 6][e & 63] = (float)v[q];
    }
    __syncthreads();
    int h = t & 15, sl = t >> 4;
    float p = 0.f;
    #pragma unroll
    for (int u = 0; u < 64; ++u) p += xr[sl][u] * Wg[(sl*64 + u)*16 + h];
    red[sl][h] = p;
    __syncthreads();
    if (t < 16) {
        float logit = gb[t];
        #pragma unroll
        for (int s2 = 0; s2 < 16; ++s2) logit += red[s2][t];
        float m = logit;
        #pragma unroll
        for (int o = 8; o; o >>= 1) m = fmaxf(m, __shfl_xor(m, o, 16));
        float e = __expf(logit - m);
        float ssum = e;
        #pragma unroll
        for (int o = 8; o; o >>= 1) ssum += __shfl_xor(ssum, o, 16);
        Gp[row*16 + t] = e / ssum;
    }
}

// ---------------- scores v3: 256 thr x 2 j each; XCD-local batches ----------
// Block bid: b = bid&7 (-> XCD b via round-robin dispatch => batch K-half
// stays L2-resident), i0 = (bid>>3)*8. LDS q-broadcast reads serve BOTH j
// columns (half the ds_read issue of v2); no max pass (|s|<=~3 bounded);
// one barrier per h via double-buffered partials.
__global__ __launch_bounds__(256) void scores_kernel(const float* __restrict__ qk,
                                                     const float* __restrict__ Gp,
                                                     const int* __restrict__ lens,
                                                     float* __restrict__ out) {
    __shared__ float qs[8][1024];
    __shared__ float gps[8][16];
    __shared__ float wredB[2][4][8];
    int bid = blockIdx.x;
    int b   = bid & 7;
    int i0  = (bid >> 3) * 8;
    int t   = threadIdx.x;
    int wave = t >> 6, lane = t & 63;
    int len = lens[b];
    const float4* qbase = (const float4*)(qk + ((size_t)b*512 + i0)*2048);
    #pragma unroll
    for (int s = 0; s < 8; ++s) {
        int e = t + s*256;
        int ti = e >> 8, c4 = e & 255;
        ((float4*)qs)[e] = qbase[ti*512 + c4];
    }
    if (t < 128) gps[t >> 4][t & 15] = Gp[((size_t)b*512 + i0 + (t >> 4))*16 + (t & 15)];
    __syncthreads();
    int j0 = t, j1 = t + 256;
    const float4* kp0 = (const float4*)(qk + ((size_t)b*512 + j0)*2048 + 1024);
    const float4* kp1 = (const float4*)(qk + ((size_t)b*512 + j1)*2048 + 1024);
    float acc0[8] = {}, acc1[8] = {}, mace[8] = {};
    for (int h = 0; h < 16; ++h) {
        float4 kv0[16], kv1[16];
        #pragma unroll
        for (int u = 0; u < 16; ++u) { kv0[u] = kp0[h*16 + u]; kv1[u] = kp1[h*16 + u]; }
        float pex0[8], pex1[8];
        #pragma unroll
        for (int ti = 0; ti < 8; ++ti) {
            const float* qrow = &qs[ti][h*64];
            float d0 = 0.f, d1 = 0.f;
            #pragma unroll
            for (int u = 0; u < 16; ++u) {
                float q0 = qrow[u*4+0], q1 = qrow[u*4+1], q2 = qrow[u*4+2], q3 = qrow[u*4+3];
                d0 += kv0[u].x*q0 + kv0[u].y*q1 + kv0[u].z*q2 + kv0[u].w*q3;
                d1 += kv1[u].x*q0 + kv1[u].y*q1 + kv1[u].z*q2 + kv1[u].w*q3;
            }
            int i = i0 + ti;
            float sc0 = (j0 > i && j0 < len) ? d0 * 0.125f : NEGC;
            float sc1 = (j1 > i && j1 < len) ? d1 * 0.125f : NEGC;
            float pe0 = __expf(sc0), pe1 = __expf(sc1);   // exp(NEG)=0 for invalid j
            pex0[ti] = pe0; pex1[ti] = pe1;
            float vv = pe0 + pe1;
            #pragma unroll
            for (int o = 32; o; o >>= 1) vv += __shfl_xor(vv, o);
            if (lane == 0) wredB[h & 1][wave][ti] = vv;
        }
        __syncthreads();
        #pragma unroll
        for (int ti = 0; ti < 8; ++ti) {
            float gs = wredB[h & 1][0][ti] + wredB[h & 1][1][ti]
                     + wredB[h & 1][2][ti] + wredB[h & 1][3][ti];
            float inv = 1.0f / gs;
            float g = gps[ti][h];
            acc0[ti] += pex0[ti] * inv * g;
            acc1[ti] += pex1[ti] * inv * g;
            mace[ti] += g * inv;
        }
    }
    #pragma unroll
    for (int ti = 0; ti < 8; ++ti) {
        int i = i0 + ti;
        float lm = NEGC + __logf(mace[ti]);
        float v0, v1;
        if (i >= len - 1) { v0 = NEGC; v1 = NEGC; }
        else {
            v0 = (j0 > i && j0 < len) ? __logf(acc0[ti]) : lm;
            v1 = (j1 > i && j1 < len) ? __logf(acc1[ti]) : lm;
        }
        out[((size_t)b*512 + i)*512 + j0] = v0;
        out[((size_t)b*512 + i)*512 + j1] = v1;
    }
}

// ---------------- vocab: bf16 logits (front of own f32 row slot) ->
//                   in-place f32 log-softmax, row staged in LDS ----------------
__global__ __launch_bounds__(256) void vocab_softmax_bf16(float* __restrict__ out) {
    __shared__ __align__(16) __bf16 srow[32000];
    __shared__ float red[8];
    size_t row = blockIdx.x;
    char* rowbase = (char*)out + row * (size_t)32000 * 4;
    const bf16x8* g8 = (const bf16x8*)rowbase;
    bf16x8* s8 = (bf16x8*)srow;
    int t = threadIdx.x, wave = t >> 6, lane = t & 63;
    float mx = -1e30f;
    for (int v = t; v < 4000; v += 256) {
        bf16x8 c = g8[v];
        s8[v] = c;
        #pragma unroll
        for (int jj = 0; jj < 8; ++jj) mx = fmaxf(mx, (float)c[jj]);
    }
    #pragma unroll
    for (int o = 32; o; o >>= 1) mx = fmaxf(mx, __shfl_xor(mx, o));
    if (lane == 0) red[wave] = mx;
    __syncthreads();
    mx = fmaxf(fmaxf(red[0], red[1]), fmaxf(red[2], red[3]));
    float sum = 0.f;
    for (int v = t; v < 4000; v += 256) {
        bf16x8 c = s8[v];
        #pragma unroll
        for (int jj = 0; jj < 8; ++jj) sum += __expf((float)c[jj] - mx);
    }
    #pragma unroll
    for (int o = 32; o; o >>= 1) sum += __shfl_xor(sum, o);
    if (lane == 0) red[4 + wave] = sum;
    __syncthreads();
    float lse = mx + __logf(red[4] + red[5] + red[6] + red[7]);
    float4* o4 = (float4*)rowbase;
    for (int u = t; u < 8000; u += 256) {           // contiguous f32 stores
        bf16x4 c = *(const bf16x4*)(srow + u*4);
        float4 a;
        a.x = (float)c[0] - lse; a.y = (float)c[1] - lse;
        a.z = (float)c[2] - lse; a.w = (float)c[3] - lse;
        o4[u] = a;
    }
}

extern "C" void kernel_launch(void* const* d_in, const int* in_sizes, int n_in,
                              void* d_out, int out_size, void* d_ws, size_t ws_size,
                              hipStream_t stream) {
    (void)in_sizes; (void)n_in; (void)out_size; (void)ws_size;
    const float* x      = (const float*)d_in[0];
    const int*   lens   = (const int*)  d_in[1];
    const float* ln_g   = (const float*)d_in[2];
    const float* ln_b   = (const float*)d_in[3];
    const float* attn_A = (const float*)d_in[4];
    const float* attn_S = (const float*)d_in[5];
    const float* attn_b = (const float*)d_in[6];
    const float* gate_A = (const float*)d_in[7];
    const float* gate_S = (const float*)d_in[8];
    const float* gate_b = (const float*)d_in[9];
    const float* lm_A   = (const float*)d_in[10];
    const float* lm_S   = (const float*)d_in[11];
    const float* lm_b   = (const float*)d_in[12];

    float* out_trans = (float*)d_out;
    float* out_vocab = out_trans + (size_t)8*512*512;

    char* ws = (char*)d_ws;
    __bf16* xn     = (__bf16*)(ws);                 //  8,388,608 B
    __bf16* WtAttn = (__bf16*)(ws + 8388608);       //  4,194,304 B
    __bf16* WtLm   = (__bf16*)(ws + 12582912);      // 65,536,000 B
    float*  Wg     = (float*) (ws + 78118912);      //     65,536 B
    float*  qkbuf  = (float*) (ws + 78184448);      // 33,554,432 B
    float*  Gp     = (float*) (ws + 111738880);     //    262,144 B

    hipLaunchKernelGGL(ln_kernel,    dim3(4096),     dim3(256), 0, stream, x, ln_g, ln_b, xn);
    hipLaunchKernelGGL(gatew_kernel, dim3(64),       dim3(256), 0, stream, gate_A, gate_S, Wg);
    hipLaunchKernelGGL(phm_build,    dim3(8, 8),     dim3(256), 0, stream, attn_A, attn_S, WtAttn, 4, 256, 512);
    hipLaunchKernelGGL(phm_build,    dim3(250, 16),  dim3(256), 0, stream, lm_A, lm_S, WtLm, 2, 512, 16000);
    hipLaunchKernelGGL((gemm_bt_t<0,0>), dim3(16, 32), dim3(256), 0, stream,
                       xn, WtAttn, attn_b, (void*)qkbuf, 4096, 2048, 1024);
    hipLaunchKernelGGL(gate_kernel,  dim3(4096),     dim3(256), 0, stream, xn, Wg, gate_b, Gp);
    hipLaunchKernelGGL(scores_kernel,dim3(512),      dim3(256), 0, stream, qkbuf, Gp, lens, out_trans);
    hipLaunchKernelGGL((gemm_bt_t<1,1>), dim3(8000),  dim3(256), 0, stream,
                       xn, WtLm, lm_b, (void*)out_vocab, 4096, 32000, 1024);
    hipLaunchKernelGGL(vocab_softmax_bf16, dim3(4096), dim3(256), 0, stream, out_vocab);
}